// Round 10
// baseline (418.298 us; speedup 1.0000x reference)
//
#include <hip/hip_runtime.h>

// GCN 2-layer + softmax head on MI355X.
// R10: GEMM pipelined: BK=64, register-prefetch double-buffer (global loads
// for tile t+1 issued before kk-loop of tile t; single LDS buffer, 2 barriers
// per tile), a_lds pad +1 (stride 65 -> 2-way store aliasing, free) fixing
// R9's residual 1.2M conflicts. Distinct kernel names for attribution.
// R9 evidence: VALUBusy 37%, occupancy 20%, barrier-serialized staging.

#define N_NODES 50000
#define N_EDGES 800000
#define N_FEAT 256
#define HIDDEN 128
#define N_CLASSES 16

#define SCAN_BLK 256
#define N_SCAN_BLKS ((N_NODES + SCAN_BLK - 1) / SCAN_BLK)   // 196

__device__ __forceinline__ int atomic_add_i32(int* p, int v) {
    return __hip_atomic_fetch_add(p, v, __ATOMIC_RELAXED, __HIP_MEMORY_SCOPE_AGENT);
}

// ---- CSR build ----------------------------------------------------------

__global__ void count_deg(const int* __restrict__ dst, int* __restrict__ cnt, int nE) {
    int e = blockIdx.x * blockDim.x + threadIdx.x;
    if (e < nE) atomic_add_i32(&cnt[dst[e]], 1);
}

__global__ __launch_bounds__(SCAN_BLK) void scan_p1(const int* __restrict__ cnt,
                                                    int* __restrict__ bsum, int n) {
    __shared__ int red[SCAN_BLK];
    int tid = threadIdx.x;
    int i = blockIdx.x * SCAN_BLK + tid;
    red[tid] = (i < n) ? cnt[i] : 0;
    __syncthreads();
    for (int off = SCAN_BLK / 2; off > 0; off >>= 1) {
        if (tid < off) red[tid] += red[tid + off];
        __syncthreads();
    }
    if (tid == 0) bsum[blockIdx.x] = red[0];
}

__global__ __launch_bounds__(SCAN_BLK) void scan_p2(const int* __restrict__ bsum,
                                                    int* __restrict__ boff, int nb) {
    __shared__ int s[SCAN_BLK];
    int tid = threadIdx.x;
    int v = (tid < nb) ? bsum[tid] : 0;
    s[tid] = v;
    __syncthreads();
    for (int off = 1; off < SCAN_BLK; off <<= 1) {
        int t = (tid >= off) ? s[tid - off] : 0;
        __syncthreads();
        s[tid] += t;
        __syncthreads();
    }
    boff[tid] = s[tid] - v;   // exclusive
}

__global__ __launch_bounds__(SCAN_BLK) void scan_p3(
    const int* __restrict__ cnt, const int* __restrict__ boff,
    int* __restrict__ row_off, int* __restrict__ cursor,
    float* __restrict__ dis, int n)
{
    __shared__ int s[SCAN_BLK];
    int tid = threadIdx.x;
    int i = blockIdx.x * SCAN_BLK + tid;
    int v = (i < n) ? cnt[i] : 0;
    s[tid] = v;
    __syncthreads();
    for (int off = 1; off < SCAN_BLK; off <<= 1) {
        int t = (tid >= off) ? s[tid - off] : 0;
        __syncthreads();
        s[tid] += t;
        __syncthreads();
    }
    int excl = boff[blockIdx.x] + s[tid] - v;
    if (i < n) {
        row_off[i] = excl;
        cursor[i]  = excl;
        dis[i]     = rsqrtf((float)(v + 1));   // +1 self-loop
    }
    if (blockIdx.x == 0 && tid == 0) row_off[n] = N_EDGES;
}

__global__ void scatter_edges(const int* __restrict__ src, const int* __restrict__ dst,
                              int* __restrict__ cursor, int* __restrict__ esrc, int nE)
{
    int e = blockIdx.x * blockDim.x + threadIdx.x;
    if (e < nE) {
        int pos = atomic_add_i32(&cursor[dst[e]], 1);
        esrc[pos] = src[e];
    }
}

// ---- GEMM with row-scale epilogue --------------------------------------
// C[M x 128] = (A[M x K] @ W[K x 128]) * dis[row]
// BM=64, BN=128, BK=64, 256 threads, 4x(4+4) outputs/thread.
// Register-prefetch: next tile's global loads issue before this tile's
// kk-loop; one LDS buffer, regs->LDS after compute barrier.
template <int K>
__device__ __forceinline__ void gemm_body(
    const float* __restrict__ A, const float* __restrict__ W,
    const float* __restrict__ dis, float* __restrict__ out, int M)
{
    constexpr int BM = 64, BN = 128, BK = 64;
    constexpr int T = K / BK;
    __shared__ float a_lds[BK][BM + 1];   // stride 65 -> store banks 2-way (free)
    __shared__ float b_lds[BK][BN];       // 64x128

    const int tid = threadIdx.x;
    const int tx = tid & 15;     // 16 column groups
    const int ty = tid >> 4;     // 16 row groups of 4
    const int row0 = blockIdx.x * BM;

    float4 areg[4], breg[8];

    // A tile: 64x64 = 1024 float4, 4/thread: r=idx>>4 (0..63), c4=(idx&15)*4
    // B tile: 64x128 = 2048 float4, 8/thread: r=idx>>5 (0..63), c4=(idx&31)*4
    auto load_tile = [&](int k0) {
#pragma unroll
        for (int p = 0; p < 4; ++p) {
            int idx = tid + p * 256;
            int r = idx >> 4, c4 = (idx & 15) * 4;
            int gr = row0 + r;
            areg[p] = (gr < M) ? *(const float4*)(A + (size_t)gr * K + k0 + c4)
                               : make_float4(0.f, 0.f, 0.f, 0.f);
        }
#pragma unroll
        for (int p = 0; p < 8; ++p) {
            int idx = tid + p * 256;
            int r = idx >> 5, c4 = (idx & 31) * 4;
            breg[p] = *(const float4*)(W + (size_t)(k0 + r) * BN + c4);
        }
    };
    auto store_tile = [&]() {
#pragma unroll
        for (int p = 0; p < 4; ++p) {
            int idx = tid + p * 256;
            int r = idx >> 4, c4 = (idx & 15) * 4;
            a_lds[c4 + 0][r] = areg[p].x;   // banks (4*c4idx + r) % 32: 2-way
            a_lds[c4 + 1][r] = areg[p].y;
            a_lds[c4 + 2][r] = areg[p].z;
            a_lds[c4 + 3][r] = areg[p].w;
        }
#pragma unroll
        for (int p = 0; p < 8; ++p) {
            int idx = tid + p * 256;
            int r = idx >> 5, c4 = (idx & 31) * 4;
            *(float4*)(&b_lds[r][c4]) = breg[p];
        }
    };

    float acc[4][8] = {};

    load_tile(0);
    store_tile();
    __syncthreads();

#pragma unroll
    for (int t = 0; t < T; ++t) {
        if (t + 1 < T) load_tile((t + 1) * BK);   // latency hides under kk-loop

#pragma unroll 8
        for (int kk = 0; kk < BK; ++kk) {
            float a[4], b[8];
            *(float4*)(a)     = *(const float4*)(&a_lds[kk][ty * 4]);      // broadcast x16
            *(float4*)(b)     = *(const float4*)(&b_lds[kk][tx * 4]);      // banks 4tx
            *(float4*)(b + 4) = *(const float4*)(&b_lds[kk][64 + tx * 4]);
#pragma unroll
            for (int i = 0; i < 4; ++i)
#pragma unroll
                for (int j = 0; j < 8; ++j)
                    acc[i][j] += a[i] * b[j];
        }

        if (t + 1 < T) {
            __syncthreads();     // everyone done reading LDS
            store_tile();        // waitcnt on areg/breg inserted here
            __syncthreads();     // LDS ready for next tile
        }
    }

#pragma unroll
    for (int i = 0; i < 4; ++i) {
        int gr = row0 + ty * 4 + i;
        if (gr < M) {
            float s = dis[gr];
            float4 o0 = make_float4(acc[i][0] * s, acc[i][1] * s, acc[i][2] * s, acc[i][3] * s);
            float4 o1 = make_float4(acc[i][4] * s, acc[i][5] * s, acc[i][6] * s, acc[i][7] * s);
            *(float4*)(out + (size_t)gr * BN + tx * 4)      = o0;
            *(float4*)(out + (size_t)gr * BN + 64 + tx * 4) = o1;
        }
    }
}

__global__ __launch_bounds__(256) void gemm_k256(
    const float* __restrict__ A, const float* __restrict__ W,
    const float* __restrict__ dis, float* __restrict__ out, int M)
{
    gemm_body<256>(A, W, dis, out, M);
}

__global__ __launch_bounds__(256) void gemm_k128(
    const float* __restrict__ A, const float* __restrict__ W,
    const float* __restrict__ dis, float* __restrict__ out, int M)
{
    gemm_body<128>(A, W, dis, out, M);
}

// ---- CSR aggregation, fused epilogue -----------------------------------
// One wave per destination node; 32 lanes x float4 cover the 128-wide row,
// half = lane>>5 selects which of 2 concurrent edges the lane reads.
// out[d] = relu(dis[d] * (g[d] + sum_e g[esrc[e]]) + bias)
__global__ __launch_bounds__(256) void aggregate_csr(
    const float* __restrict__ g, const int* __restrict__ row_off,
    const int* __restrict__ esrc, const float* __restrict__ dis,
    const float* __restrict__ bias, float* __restrict__ out, int M)
{
    const int wid  = (blockIdx.x * blockDim.x + threadIdx.x) >> 6;
    const int lane = threadIdx.x & 63;
    if (wid >= M) return;

    const int half = lane >> 5;        // 0 or 1: which edge of the pair
    const int col  = (lane & 31) * 4;  // float4 column

    const int beg = row_off[wid];
    const int end = row_off[wid + 1];

    float4 sum = make_float4(0.f, 0.f, 0.f, 0.f);

    for (int e0 = beg; e0 < end; e0 += 64) {
        const int cnt = min(64, end - e0);
        int myidx = (lane < cnt) ? esrc[e0 + lane] : 0;
        int j = 0;
        for (; j + 8 <= cnt; j += 8) {
            int s0 = __shfl(myidx, j + half);
            int s1 = __shfl(myidx, j + 2 + half);
            int s2 = __shfl(myidx, j + 4 + half);
            int s3 = __shfl(myidx, j + 6 + half);
            float4 v0 = *(const float4*)(g + (size_t)s0 * HIDDEN + col);
            float4 v1 = *(const float4*)(g + (size_t)s1 * HIDDEN + col);
            float4 v2 = *(const float4*)(g + (size_t)s2 * HIDDEN + col);
            float4 v3 = *(const float4*)(g + (size_t)s3 * HIDDEN + col);
            sum.x += v0.x + v1.x + v2.x + v3.x;
            sum.y += v0.y + v1.y + v2.y + v3.y;
            sum.z += v0.z + v1.z + v2.z + v3.z;
            sum.w += v0.w + v1.w + v2.w + v3.w;
        }
        for (; j + 2 <= cnt; j += 2) {
            int s = __shfl(myidx, j + half);
            float4 v = *(const float4*)(g + (size_t)s * HIDDEN + col);
            sum.x += v.x; sum.y += v.y; sum.z += v.z; sum.w += v.w;
        }
        if (j < cnt) {   // odd tail: one edge, half==0 lanes only
            int s = __shfl(myidx, j);
            if (half == 0) {
                float4 v = *(const float4*)(g + (size_t)s * HIDDEN + col);
                sum.x += v.x; sum.y += v.y; sum.z += v.z; sum.w += v.w;
            }
        }
    }

    // combine the two edge-halves (lane <-> lane^32)
    sum.x += __shfl_xor(sum.x, 32);
    sum.y += __shfl_xor(sum.y, 32);
    sum.z += __shfl_xor(sum.z, 32);
    sum.w += __shfl_xor(sum.w, 32);

    if (half == 0) {
        float4 self = *(const float4*)(g + (size_t)wid * HIDDEN + col);
        const float sc = dis[wid];
        float4 bv = *(const float4*)(bias + col);
        float4 o;
        o.x = fmaxf(sc * (sum.x + self.x) + bv.x, 0.f);
        o.y = fmaxf(sc * (sum.y + self.y) + bv.y, 0.f);
        o.z = fmaxf(sc * (sum.z + self.z) + bv.z, 0.f);
        o.w = fmaxf(sc * (sum.w + self.w) + bv.w, 0.f);
        *(float4*)(out + (size_t)wid * HIDDEN + col) = o;
    }
}

// ---- head ---------------------------------------------------------------
__global__ void head_softmax(const float* __restrict__ h, const float* __restrict__ Wout,
                             const float* __restrict__ bout, float* __restrict__ out, int M)
{
    __shared__ float w[HIDDEN * N_CLASSES];
    for (int i = threadIdx.x; i < HIDDEN * N_CLASSES; i += blockDim.x) w[i] = Wout[i];
    __syncthreads();

    int node = blockIdx.x * blockDim.x + threadIdx.x;
    if (node >= M) return;

    const float4* hp = (const float4*)(h + (size_t)node * HIDDEN);
    float acc[N_CLASSES];
#pragma unroll
    for (int c = 0; c < N_CLASSES; ++c) acc[c] = bout[c];
#pragma unroll
    for (int k4 = 0; k4 < HIDDEN / 4; ++k4) {
        float4 hv = hp[k4];
#pragma unroll
        for (int c = 0; c < N_CLASSES; ++c) {
            acc[c] += hv.x * w[(k4 * 4 + 0) * N_CLASSES + c]
                    + hv.y * w[(k4 * 4 + 1) * N_CLASSES + c]
                    + hv.z * w[(k4 * 4 + 2) * N_CLASSES + c]
                    + hv.w * w[(k4 * 4 + 3) * N_CLASSES + c];
        }
    }
    float m = acc[0];
#pragma unroll
    for (int c = 1; c < N_CLASSES; ++c) m = fmaxf(m, acc[c]);
    float sum = 0.f;
#pragma unroll
    for (int c = 0; c < N_CLASSES; ++c) { acc[c] = expf(acc[c] - m); sum += acc[c]; }
    float inv = 1.0f / sum;
#pragma unroll
    for (int c4 = 0; c4 < N_CLASSES; c4 += 4) {
        float4 o = make_float4(acc[c4] * inv, acc[c4 + 1] * inv, acc[c4 + 2] * inv, acc[c4 + 3] * inv);
        *(float4*)(out + (size_t)node * N_CLASSES + c4) = o;
    }
}

// ---- launch -------------------------------------------------------------
extern "C" void kernel_launch(void* const* d_in, const int* in_sizes, int n_in,
                              void* d_out, int out_size, void* d_ws, size_t ws_size,
                              hipStream_t stream)
{
    const float* x    = (const float*)d_in[0];
    const int*   ei   = (const int*)d_in[1];   // [2, N_EDGES]; row0=src, row1=dst
    const float* W1   = (const float*)d_in[2];
    const float* b1   = (const float*)d_in[3];
    const float* W2   = (const float*)d_in[4];
    const float* b2   = (const float*)d_in[5];
    const float* Wout = (const float*)d_in[6];
    const float* bout = (const float*)d_in[7];
    float* out = (float*)d_out;

    const int* src = ei;
    const int* dst = ei + N_EDGES;

    // Workspace layout (4B units):
    float* dis     = (float*)d_ws;             // 50176
    int*   cnt     = (int*)(dis + 50176);      // 50176
    int*   row_off = cnt + 50176;              // 50432 (n+1, padded)
    int*   cursor  = row_off + 50432;          // 50176
    int*   esrc    = cursor + 50176;           // 800000
    int*   bsum    = esrc + 800000;            // 256
    int*   boff    = bsum + 256;               // 256
    float* A       = (float*)(boff + 256);     // 6.4M
    float* B       = A + (size_t)N_NODES * HIDDEN;

    // CSR build
    hipMemsetAsync(cnt, 0, 50176 * sizeof(int), stream);
    count_deg<<<(N_EDGES + 255) / 256, 256, 0, stream>>>(dst, cnt, N_EDGES);
    scan_p1<<<N_SCAN_BLKS, SCAN_BLK, 0, stream>>>(cnt, bsum, N_NODES);
    scan_p2<<<1, SCAN_BLK, 0, stream>>>(bsum, boff, N_SCAN_BLKS);
    scan_p3<<<N_SCAN_BLKS, SCAN_BLK, 0, stream>>>(cnt, boff, row_off, cursor, dis, N_NODES);
    scatter_edges<<<(N_EDGES + 255) / 256, 256, 0, stream>>>(src, dst, cursor, esrc, N_EDGES);

    const int aggGrid = (N_NODES * 64 + 255) / 256;   // one wave per node

    // Layer 1
    gemm_k256<<<(N_NODES + 63) / 64, 256, 0, stream>>>(x, W1, dis, A, N_NODES);
    aggregate_csr<<<aggGrid, 256, 0, stream>>>(A, row_off, esrc, dis, b1, B, N_NODES);

    // Layer 2
    gemm_k128<<<(N_NODES + 63) / 64, 256, 0, stream>>>(B, W2, dis, A, N_NODES);
    aggregate_csr<<<aggGrid, 256, 0, stream>>>(A, row_off, esrc, dis, b2, B, N_NODES);

    // Head
    head_softmax<<<(N_NODES + 255) / 256, 256, 0, stream>>>(B, Wout, bout, out, N_NODES);
}

// Round 13
// 408.657 us; speedup vs baseline: 1.0236x; 1.0236x over previous
//
#include <hip/hip_runtime.h>

// GCN 2-layer + softmax head on MI355X.
// R11 (2nd resubmit; acquisition timeouts, never benched): R10's
// register-prefetch pipeline REWRITTEN spill-free. R10 evidence: WRITE_SIZE
// 107MB (4x output), FETCH +20MB, dispatch-0 VALUBusy 1% -> lambda-captured
// staging arrays went to scratch. Fix: 12 named float4 staging regs via
// macros (no arrays, no lambdas) + __launch_bounds__(256,3).
// Pipeline: BK=64, global loads for tile t+1 issue before kk-loop of tile t;
// single LDS buffer, 2 barriers/tile; a_lds pad +1 (2-way store, free).

#define N_NODES 50000
#define N_EDGES 800000
#define N_FEAT 256
#define HIDDEN 128
#define N_CLASSES 16

#define SCAN_BLK 256
#define N_SCAN_BLKS ((N_NODES + SCAN_BLK - 1) / SCAN_BLK)   // 196

__device__ __forceinline__ int atomic_add_i32(int* p, int v) {
    return __hip_atomic_fetch_add(p, v, __ATOMIC_RELAXED, __HIP_MEMORY_SCOPE_AGENT);
}

// ---- CSR build ----------------------------------------------------------

__global__ void count_deg(const int* __restrict__ dst, int* __restrict__ cnt, int nE) {
    int e = blockIdx.x * blockDim.x + threadIdx.x;
    if (e < nE) atomic_add_i32(&cnt[dst[e]], 1);
}

__global__ __launch_bounds__(SCAN_BLK) void scan_p1(const int* __restrict__ cnt,
                                                    int* __restrict__ bsum, int n) {
    __shared__ int red[SCAN_BLK];
    int tid = threadIdx.x;
    int i = blockIdx.x * SCAN_BLK + tid;
    red[tid] = (i < n) ? cnt[i] : 0;
    __syncthreads();
    for (int off = SCAN_BLK / 2; off > 0; off >>= 1) {
        if (tid < off) red[tid] += red[tid + off];
        __syncthreads();
    }
    if (tid == 0) bsum[blockIdx.x] = red[0];
}

__global__ __launch_bounds__(SCAN_BLK) void scan_p2(const int* __restrict__ bsum,
                                                    int* __restrict__ boff, int nb) {
    __shared__ int s[SCAN_BLK];
    int tid = threadIdx.x;
    int v = (tid < nb) ? bsum[tid] : 0;
    s[tid] = v;
    __syncthreads();
    for (int off = 1; off < SCAN_BLK; off <<= 1) {
        int t = (tid >= off) ? s[tid - off] : 0;
        __syncthreads();
        s[tid] += t;
        __syncthreads();
    }
    boff[tid] = s[tid] - v;   // exclusive
}

__global__ __launch_bounds__(SCAN_BLK) void scan_p3(
    const int* __restrict__ cnt, const int* __restrict__ boff,
    int* __restrict__ row_off, int* __restrict__ cursor,
    float* __restrict__ dis, int n)
{
    __shared__ int s[SCAN_BLK];
    int tid = threadIdx.x;
    int i = blockIdx.x * SCAN_BLK + tid;
    int v = (i < n) ? cnt[i] : 0;
    s[tid] = v;
    __syncthreads();
    for (int off = 1; off < SCAN_BLK; off <<= 1) {
        int t = (tid >= off) ? s[tid - off] : 0;
        __syncthreads();
        s[tid] += t;
        __syncthreads();
    }
    int excl = boff[blockIdx.x] + s[tid] - v;
    if (i < n) {
        row_off[i] = excl;
        cursor[i]  = excl;
        dis[i]     = rsqrtf((float)(v + 1));   // +1 self-loop
    }
    if (blockIdx.x == 0 && tid == 0) row_off[n] = N_EDGES;
}

__global__ void scatter_edges(const int* __restrict__ src, const int* __restrict__ dst,
                              int* __restrict__ cursor, int* __restrict__ esrc, int nE)
{
    int e = blockIdx.x * blockDim.x + threadIdx.x;
    if (e < nE) {
        int pos = atomic_add_i32(&cursor[dst[e]], 1);
        esrc[pos] = src[e];
    }
}

// ---- GEMM with row-scale epilogue --------------------------------------
// C[M x 128] = (A[M x K] @ W[K x 128]) * dis[row]
// BM=64, BN=128, BK=64, 256 threads, 4x(4+4) outputs/thread.
// Register-prefetch pipeline with NAMED staging regs (spill-proof).

__device__ __forceinline__ float4 ldA4(const float* __restrict__ A, int gr,
                                       int K, int off, int M) {
    return (gr < M) ? *(const float4*)(A + (size_t)gr * K + off)
                    : make_float4(0.f, 0.f, 0.f, 0.f);
}

// A: thread stages rows rA+{0,16,32,48}, cols cA..cA+3 (of 64-wide k-slab)
// B: thread stages rows rB+{0,8,...,56}, cols cB..cB+3 (of 128-wide slab)
#define LOAD_T(k0)                                                          \
    ar0 = ldA4(A, row0 + rA,      K, (k0) + cA, M);                         \
    ar1 = ldA4(A, row0 + rA + 16, K, (k0) + cA, M);                         \
    ar2 = ldA4(A, row0 + rA + 32, K, (k0) + cA, M);                         \
    ar3 = ldA4(A, row0 + rA + 48, K, (k0) + cA, M);                         \
    br0 = *(const float4*)(W + (size_t)((k0) + rB     ) * 128 + cB);        \
    br1 = *(const float4*)(W + (size_t)((k0) + rB +  8) * 128 + cB);        \
    br2 = *(const float4*)(W + (size_t)((k0) + rB + 16) * 128 + cB);        \
    br3 = *(const float4*)(W + (size_t)((k0) + rB + 24) * 128 + cB);        \
    br4 = *(const float4*)(W + (size_t)((k0) + rB + 32) * 128 + cB);        \
    br5 = *(const float4*)(W + (size_t)((k0) + rB + 40) * 128 + cB);        \
    br6 = *(const float4*)(W + (size_t)((k0) + rB + 48) * 128 + cB);        \
    br7 = *(const float4*)(W + (size_t)((k0) + rB + 56) * 128 + cB);

#define STORE_A(v, r)                                                       \
    a_lds[cA + 0][r] = v.x; a_lds[cA + 1][r] = v.y;                         \
    a_lds[cA + 2][r] = v.z; a_lds[cA + 3][r] = v.w;

#define STORE_T()                                                           \
    STORE_A(ar0, rA)      STORE_A(ar1, rA + 16)                             \
    STORE_A(ar2, rA + 32) STORE_A(ar3, rA + 48)                             \
    *(float4*)(&b_lds[rB     ][cB]) = br0;                                  \
    *(float4*)(&b_lds[rB +  8][cB]) = br1;                                  \
    *(float4*)(&b_lds[rB + 16][cB]) = br2;                                  \
    *(float4*)(&b_lds[rB + 24][cB]) = br3;                                  \
    *(float4*)(&b_lds[rB + 32][cB]) = br4;                                  \
    *(float4*)(&b_lds[rB + 40][cB]) = br5;                                  \
    *(float4*)(&b_lds[rB + 48][cB]) = br6;                                  \
    *(float4*)(&b_lds[rB + 56][cB]) = br7;

template <int K>
__device__ __forceinline__ void gemm_body(
    const float* __restrict__ A, const float* __restrict__ W,
    const float* __restrict__ dis, float* __restrict__ out, int M)
{
    constexpr int BM = 64, BN = 128, BK = 64;
    constexpr int T = K / BK;
    __shared__ float a_lds[BK][BM + 1];   // stride 65: 2-way store alias (free)
    __shared__ float b_lds[BK][BN];

    const int tid = threadIdx.x;
    const int tx = tid & 15;
    const int ty = tid >> 4;
    const int row0 = blockIdx.x * BM;
    const int rA = tid >> 4;          // 0..15 (+16p)
    const int cA = (tid & 15) * 4;    // 0..60
    const int rB = tid >> 5;          // 0..7  (+8p)
    const int cB = (tid & 31) * 4;    // 0..124

    float4 ar0, ar1, ar2, ar3;
    float4 br0, br1, br2, br3, br4, br5, br6, br7;

    float acc[4][8] = {};

    LOAD_T(0)
    STORE_T()
    __syncthreads();

#pragma unroll
    for (int t = 0; t < T; ++t) {
        if (t + 1 < T) { LOAD_T((t + 1) * BK) }   // hides under kk-loop

#pragma unroll 8
        for (int kk = 0; kk < BK; ++kk) {
            float a[4], b[8];
            *(float4*)(a)     = *(const float4*)(&a_lds[kk][ty * 4]);      // bcast x16
            *(float4*)(b)     = *(const float4*)(&b_lds[kk][tx * 4]);
            *(float4*)(b + 4) = *(const float4*)(&b_lds[kk][64 + tx * 4]);
#pragma unroll
            for (int i = 0; i < 4; ++i)
#pragma unroll
                for (int j = 0; j < 8; ++j)
                    acc[i][j] += a[i] * b[j];
        }

        if (t + 1 < T) {
            __syncthreads();
            STORE_T()
            __syncthreads();
        }
    }

#pragma unroll
    for (int i = 0; i < 4; ++i) {
        int gr = row0 + ty * 4 + i;
        if (gr < M) {
            float s = dis[gr];
            float4 o0 = make_float4(acc[i][0] * s, acc[i][1] * s, acc[i][2] * s, acc[i][3] * s);
            float4 o1 = make_float4(acc[i][4] * s, acc[i][5] * s, acc[i][6] * s, acc[i][7] * s);
            *(float4*)(out + (size_t)gr * BN + tx * 4)      = o0;
            *(float4*)(out + (size_t)gr * BN + 64 + tx * 4) = o1;
        }
    }
}

__global__ __launch_bounds__(256, 3) void gemm_k256(
    const float* __restrict__ A, const float* __restrict__ W,
    const float* __restrict__ dis, float* __restrict__ out, int M)
{
    gemm_body<256>(A, W, dis, out, M);
}

__global__ __launch_bounds__(256, 3) void gemm_k128(
    const float* __restrict__ A, const float* __restrict__ W,
    const float* __restrict__ dis, float* __restrict__ out, int M)
{
    gemm_body<128>(A, W, dis, out, M);
}

// ---- CSR aggregation, fused epilogue -----------------------------------
// One wave per destination node; 32 lanes x float4 cover the 128-wide row,
// half = lane>>5 selects which of 2 concurrent edges the lane reads.
// out[d] = relu(dis[d] * (g[d] + sum_e g[esrc[e]]) + bias)
__global__ __launch_bounds__(256) void aggregate_csr(
    const float* __restrict__ g, const int* __restrict__ row_off,
    const int* __restrict__ esrc, const float* __restrict__ dis,
    const float* __restrict__ bias, float* __restrict__ out, int M)
{
    const int wid  = (blockIdx.x * blockDim.x + threadIdx.x) >> 6;
    const int lane = threadIdx.x & 63;
    if (wid >= M) return;

    const int half = lane >> 5;        // 0 or 1: which edge of the pair
    const int col  = (lane & 31) * 4;  // float4 column

    const int beg = row_off[wid];
    const int end = row_off[wid + 1];

    float4 sum = make_float4(0.f, 0.f, 0.f, 0.f);

    for (int e0 = beg; e0 < end; e0 += 64) {
        const int cnt = min(64, end - e0);
        int myidx = (lane < cnt) ? esrc[e0 + lane] : 0;
        int j = 0;
        for (; j + 8 <= cnt; j += 8) {
            int s0 = __shfl(myidx, j + half);
            int s1 = __shfl(myidx, j + 2 + half);
            int s2 = __shfl(myidx, j + 4 + half);
            int s3 = __shfl(myidx, j + 6 + half);
            float4 v0 = *(const float4*)(g + (size_t)s0 * HIDDEN + col);
            float4 v1 = *(const float4*)(g + (size_t)s1 * HIDDEN + col);
            float4 v2 = *(const float4*)(g + (size_t)s2 * HIDDEN + col);
            float4 v3 = *(const float4*)(g + (size_t)s3 * HIDDEN + col);
            sum.x += v0.x + v1.x + v2.x + v3.x;
            sum.y += v0.y + v1.y + v2.y + v3.y;
            sum.z += v0.z + v1.z + v2.z + v3.z;
            sum.w += v0.w + v1.w + v2.w + v3.w;
        }
        for (; j + 2 <= cnt; j += 2) {
            int s = __shfl(myidx, j + half);
            float4 v = *(const float4*)(g + (size_t)s * HIDDEN + col);
            sum.x += v.x; sum.y += v.y; sum.z += v.z; sum.w += v.w;
        }
        if (j < cnt) {   // odd tail: one edge, half==0 lanes only
            int s = __shfl(myidx, j);
            if (half == 0) {
                float4 v = *(const float4*)(g + (size_t)s * HIDDEN + col);
                sum.x += v.x; sum.y += v.y; sum.z += v.z; sum.w += v.w;
            }
        }
    }

    // combine the two edge-halves (lane <-> lane^32)
    sum.x += __shfl_xor(sum.x, 32);
    sum.y += __shfl_xor(sum.y, 32);
    sum.z += __shfl_xor(sum.z, 32);
    sum.w += __shfl_xor(sum.w, 32);

    if (half == 0) {
        float4 self = *(const float4*)(g + (size_t)wid * HIDDEN + col);
        const float sc = dis[wid];
        float4 bv = *(const float4*)(bias + col);
        float4 o;
        o.x = fmaxf(sc * (sum.x + self.x) + bv.x, 0.f);
        o.y = fmaxf(sc * (sum.y + self.y) + bv.y, 0.f);
        o.z = fmaxf(sc * (sum.z + self.z) + bv.z, 0.f);
        o.w = fmaxf(sc * (sum.w + self.w) + bv.w, 0.f);
        *(float4*)(out + (size_t)wid * HIDDEN + col) = o;
    }
}

// ---- head ---------------------------------------------------------------
__global__ void head_softmax(const float* __restrict__ h, const float* __restrict__ Wout,
                             const float* __restrict__ bout, float* __restrict__ out, int M)
{
    __shared__ float w[HIDDEN * N_CLASSES];
    for (int i = threadIdx.x; i < HIDDEN * N_CLASSES; i += blockDim.x) w[i] = Wout[i];
    __syncthreads();

    int node = blockIdx.x * blockDim.x + threadIdx.x;
    if (node >= M) return;

    const float4* hp = (const float4*)(h + (size_t)node * HIDDEN);
    float acc[N_CLASSES];
#pragma unroll
    for (int c = 0; c < N_CLASSES; ++c) acc[c] = bout[c];
#pragma unroll
    for (int k4 = 0; k4 < HIDDEN / 4; ++k4) {
        float4 hv = hp[k4];
#pragma unroll
        for (int c = 0; c < N_CLASSES; ++c) {
            acc[c] += hv.x * w[(k4 * 4 + 0) * N_CLASSES + c]
                    + hv.y * w[(k4 * 4 + 1) * N_CLASSES + c]
                    + hv.z * w[(k4 * 4 + 2) * N_CLASSES + c]
                    + hv.w * w[(k4 * 4 + 3) * N_CLASSES + c];
        }
    }
    float m = acc[0];
#pragma unroll
    for (int c = 1; c < N_CLASSES; ++c) m = fmaxf(m, acc[c]);
    float sum = 0.f;
#pragma unroll
    for (int c = 0; c < N_CLASSES; ++c) { acc[c] = expf(acc[c] - m); sum += acc[c]; }
    float inv = 1.0f / sum;
#pragma unroll
    for (int c4 = 0; c4 < N_CLASSES; c4 += 4) {
        float4 o = make_float4(acc[c4] * inv, acc[c4 + 1] * inv, acc[c4 + 2] * inv, acc[c4 + 3] * inv);
        *(float4*)(out + (size_t)node * N_CLASSES + c4) = o;
    }
}

// ---- launch -------------------------------------------------------------
extern "C" void kernel_launch(void* const* d_in, const int* in_sizes, int n_in,
                              void* d_out, int out_size, void* d_ws, size_t ws_size,
                              hipStream_t stream)
{
    const float* x    = (const float*)d_in[0];
    const int*   ei   = (const int*)d_in[1];   // [2, N_EDGES]; row0=src, row1=dst
    const float* W1   = (const float*)d_in[2];
    const float* b1   = (const float*)d_in[3];
    const float* W2   = (const float*)d_in[4];
    const float* b2   = (const float*)d_in[5];
    const float* Wout = (const float*)d_in[6];
    const float* bout = (const float*)d_in[7];
    float* out = (float*)d_out;

    const int* src = ei;
    const int* dst = ei + N_EDGES;

    // Workspace layout (4B units):
    float* dis     = (float*)d_ws;             // 50176
    int*   cnt     = (int*)(dis + 50176);      // 50176
    int*   row_off = cnt + 50176;              // 50432 (n+1, padded)
    int*   cursor  = row_off + 50432;          // 50176
    int*   esrc    = cursor + 50176;           // 800000
    int*   bsum    = esrc + 800000;            // 256
    int*   boff    = bsum + 256;               // 256
    float* A       = (float*)(boff + 256);     // 6.4M
    float* B       = A + (size_t)N_NODES * HIDDEN;

    // CSR build
    hipMemsetAsync(cnt, 0, 50176 * sizeof(int), stream);
    count_deg<<<(N_EDGES + 255) / 256, 256, 0, stream>>>(dst, cnt, N_EDGES);
    scan_p1<<<N_SCAN_BLKS, SCAN_BLK, 0, stream>>>(cnt, bsum, N_NODES);
    scan_p2<<<1, SCAN_BLK, 0, stream>>>(bsum, boff, N_SCAN_BLKS);
    scan_p3<<<N_SCAN_BLKS, SCAN_BLK, 0, stream>>>(cnt, boff, row_off, cursor, dis, N_NODES);
    scatter_edges<<<(N_EDGES + 255) / 256, 256, 0, stream>>>(src, dst, cursor, esrc, N_EDGES);

    const int aggGrid = (N_NODES * 64 + 255) / 256;   // one wave per node

    // Layer 1
    gemm_k256<<<(N_NODES + 63) / 64, 256, 0, stream>>>(x, W1, dis, A, N_NODES);
    aggregate_csr<<<aggGrid, 256, 0, stream>>>(A, row_off, esrc, dis, b1, B, N_NODES);

    // Layer 2
    gemm_k128<<<(N_NODES + 63) / 64, 256, 0, stream>>>(B, W2, dis, A, N_NODES);
    aggregate_csr<<<aggGrid, 256, 0, stream>>>(A, row_off, esrc, dis, b2, B, N_NODES);

    // Head
    head_softmax<<<(N_NODES + 255) / 256, 256, 0, stream>>>(B, Wout, bout, out, N_NODES);
}